// Round 1
// baseline (2116.972 us; speedup 1.0000x reference)
//
#include <hip/hip_runtime.h>
#include <hip/hip_bf16.h>

// EncoderCell: fp32 correctness-first baseline.
//  - gemm_f32: 64x64 tile, 256 thr (16x16), 4x4 microtile, LDS stride 68 (<=2-way bank alias, free)
//  - attn_f32: flash-style, block = (b, h, 64 q-rows), 64-row K/V tiles, online softmax
//  - ln_res:   mode 0: out = LN(a)*g+be + r   (LN1);  mode 1: out = LN(a+r)*g+be (LN2)
// ws layout (floats): qh | kh | vh | z | h1(4*ND)  = 8*ND = 128 MiB; zd->qh, x->kh, y->vh reuse.

#define D_MODEL 1024
#define NHEAD   16
#define DHEAD   64
#define SEQ     2048
#define LNEPS   1e-5f

// ------------------------------------------------------------------
// Generic fp32 GEMM: C[M,N] = A[M,K] @ B[K,N]  (+bias, +relu)
// ep: 0 = none, 1 = +bias, 2 = +bias then relu
// M,N multiples of 64; K multiple of 16.
// ------------------------------------------------------------------
__global__ __launch_bounds__(256) void gemm_f32(
    const float* __restrict__ A, const float* __restrict__ B,
    float* __restrict__ C, int M, int N, int K,
    const float* __restrict__ bias, int ep)
{
    __shared__ float As[16 * 68];   // As[kk][mm], stride 68
    __shared__ float Bs[16 * 68];   // Bs[kk][nn], stride 68

    const int t  = threadIdx.x;
    const int m0 = blockIdx.y * 64;
    const int n0 = blockIdx.x * 64;
    const int tm = (t >> 4) * 4;    // 4 M-rows per thread
    const int tn = (t & 15) * 4;    // 4 N-cols per thread

    const int amm = t >> 2;          // A load: row within tile
    const int akk = (t & 3) * 4;     // A load: 4 consecutive k
    const int bkk = t >> 4;          // B load: k row
    const int bnn = (t & 15) * 4;    // B load: 4 consecutive n

    float acc[4][4] = {};

    for (int k0 = 0; k0 < K; k0 += 16) {
        __syncthreads();
        // A tile -> LDS (transposed to [kk][mm])
        float4 a4 = *(const float4*)&A[(size_t)(m0 + amm) * K + k0 + akk];
        As[(akk + 0) * 68 + amm] = a4.x;
        As[(akk + 1) * 68 + amm] = a4.y;
        As[(akk + 2) * 68 + amm] = a4.z;
        As[(akk + 3) * 68 + amm] = a4.w;
        // B tile -> LDS
        *(float4*)&Bs[bkk * 68 + bnn] =
            *(const float4*)&B[(size_t)(k0 + bkk) * N + n0 + bnn];
        __syncthreads();

        #pragma unroll
        for (int kk = 0; kk < 16; kk++) {
            float4 av = *(float4*)&As[kk * 68 + tm];
            float4 bv = *(float4*)&Bs[kk * 68 + tn];
            const float aa[4] = {av.x, av.y, av.z, av.w};
            const float bb[4] = {bv.x, bv.y, bv.z, bv.w};
            #pragma unroll
            for (int i = 0; i < 4; i++)
                #pragma unroll
                for (int j = 0; j < 4; j++)
                    acc[i][j] += aa[i] * bb[j];
        }
    }

    float4 bv4 = make_float4(0.f, 0.f, 0.f, 0.f);
    if (ep) bv4 = *(const float4*)&bias[n0 + tn];
    #pragma unroll
    for (int i = 0; i < 4; i++) {
        float4 o;
        o.x = acc[i][0] + bv4.x;
        o.y = acc[i][1] + bv4.y;
        o.z = acc[i][2] + bv4.z;
        o.w = acc[i][3] + bv4.w;
        if (ep == 2) {
            o.x = fmaxf(o.x, 0.f); o.y = fmaxf(o.y, 0.f);
            o.z = fmaxf(o.z, 0.f); o.w = fmaxf(o.w, 0.f);
        }
        *(float4*)&C[(size_t)(m0 + tm + i) * N + n0 + tn] = o;
    }
}

// ------------------------------------------------------------------
// Flash-style attention, fp32.
// grid = B * H * (SEQ/64); block = 256 (16x16 threads)
// Per block: 64 q-rows of head h in batch b. Online softmax over 32 K-tiles.
// Thread (tq,tk): score/O microtile rows qi = tq*4+0..3; score cols kj = tk+16j;
//                 O cols c = tk*4+0..3.
// ------------------------------------------------------------------
__global__ __launch_bounds__(256) void attn_f32(
    const float* __restrict__ qh, const float* __restrict__ kh,
    const float* __restrict__ vh, const float* __restrict__ mask,
    float* __restrict__ z)
{
    __shared__ float qs[64 * 68];
    __shared__ float ks[64 * 68];
    __shared__ float vs[64 * 68];
    __shared__ float sc[64 * 68];     // p (post-exp probabilities)
    __shared__ float red[64 * 36];    // [qi][0..15]=max partials, [qi][16..31]=sum partials

    const int t   = threadIdx.x;
    const int bid = blockIdx.x;
    const int qt  = bid & 31;
    const int h   = (bid >> 5) & 15;
    const int b   = bid >> 9;
    const int q0  = qt * 64;
    const int tq  = t >> 4;
    const int tk  = t & 15;
    const size_t rowbase = (size_t)b * SEQ;
    const int colbase = h * DHEAD;

    // load Q tile
    #pragma unroll
    for (int i = 0; i < 4; i++) {
        int f = t + i * 256;
        int r = f >> 4, c4 = f & 15;
        *(float4*)&qs[r * 68 + c4 * 4] =
            *(const float4*)&qh[(rowbase + q0 + r) * D_MODEL + colbase + c4 * 4];
    }

    float m_i[4], l_i[4], accv[4][4];
    #pragma unroll
    for (int i = 0; i < 4; i++) {
        m_i[i] = -1e30f; l_i[i] = 0.f;
        #pragma unroll
        for (int j = 0; j < 4; j++) accv[i][j] = 0.f;
    }
    __syncthreads();

    for (int kt = 0; kt < SEQ / 64; kt++) {
        const int k0 = kt * 64;
        __syncthreads();   // prior-iteration LDS reads complete
        // load K,V tiles
        #pragma unroll
        for (int i = 0; i < 4; i++) {
            int f = t + i * 256;
            int r = f >> 4, c4 = f & 15;
            *(float4*)&ks[r * 68 + c4 * 4] =
                *(const float4*)&kh[(rowbase + k0 + r) * D_MODEL + colbase + c4 * 4];
            *(float4*)&vs[r * 68 + c4 * 4] =
                *(const float4*)&vh[(rowbase + k0 + r) * D_MODEL + colbase + c4 * 4];
        }
        __syncthreads();

        // scores: s[i][j] = q[qi] . k[kj],  qi = tq*4+i, kj = tk+16j
        float s[4][4] = {};
        #pragma unroll
        for (int d4 = 0; d4 < 16; d4++) {
            float4 qa[4], kb[4];
            #pragma unroll
            for (int i = 0; i < 4; i++)
                qa[i] = *(float4*)&qs[(tq * 4 + i) * 68 + d4 * 4];
            #pragma unroll
            for (int j = 0; j < 4; j++)
                kb[j] = *(float4*)&ks[(tk + 16 * j) * 68 + d4 * 4];
            #pragma unroll
            for (int i = 0; i < 4; i++)
                #pragma unroll
                for (int j = 0; j < 4; j++)
                    s[i][j] += qa[i].x * kb[j].x + qa[i].y * kb[j].y +
                               qa[i].z * kb[j].z + qa[i].w * kb[j].w;
        }
        // scale + mask
        #pragma unroll
        for (int i = 0; i < 4; i++)
            #pragma unroll
            for (int j = 0; j < 4; j++)
                s[i][j] = s[i][j] * 0.125f +
                          mask[(size_t)(q0 + tq * 4 + i) * SEQ + k0 + tk + 16 * j];

        // per-thread row maxima -> red
        #pragma unroll
        for (int i = 0; i < 4; i++) {
            float lm = fmaxf(fmaxf(s[i][0], s[i][1]), fmaxf(s[i][2], s[i][3]));
            red[(tq * 4 + i) * 36 + tk] = lm;
        }
        __syncthreads();

        float mnew[4], alpha[4];
        #pragma unroll
        for (int i = 0; i < 4; i++) {
            float mt = -1e30f;
            #pragma unroll
            for (int u = 0; u < 16; u++)
                mt = fmaxf(mt, red[(tq * 4 + i) * 36 + u]);
            mnew[i]  = fmaxf(m_i[i], mt);
            alpha[i] = __expf(m_i[i] - mnew[i]);
            m_i[i]   = mnew[i];
        }
        // p = exp(s - mnew) -> sc; partial sums -> red[.. 16+tk]
        #pragma unroll
        for (int i = 0; i < 4; i++) {
            float psum = 0.f;
            #pragma unroll
            for (int j = 0; j < 4; j++) {
                float p = __expf(s[i][j] - mnew[i]);
                sc[(tq * 4 + i) * 68 + tk + 16 * j] = p;
                psum += p;
            }
            red[(tq * 4 + i) * 36 + 16 + tk] = psum;
        }
        __syncthreads();

        // l update + rescale acc
        #pragma unroll
        for (int i = 0; i < 4; i++) {
            float ss = 0.f;
            #pragma unroll
            for (int u = 0; u < 16; u++)
                ss += red[(tq * 4 + i) * 36 + 16 + u];
            l_i[i] = l_i[i] * alpha[i] + ss;
            #pragma unroll
            for (int c = 0; c < 4; c++) accv[i][c] *= alpha[i];
        }
        // PV: acc[i][c] += p[qi][j] * v[j][c]
        #pragma unroll 8
        for (int j = 0; j < 64; j++) {
            float4 vv = *(const float4*)&vs[j * 68 + tk * 4];
            float pp[4];
            #pragma unroll
            for (int i = 0; i < 4; i++) pp[i] = sc[(tq * 4 + i) * 68 + j];
            #pragma unroll
            for (int i = 0; i < 4; i++) {
                accv[i][0] += pp[i] * vv.x;
                accv[i][1] += pp[i] * vv.y;
                accv[i][2] += pp[i] * vv.z;
                accv[i][3] += pp[i] * vv.w;
            }
        }
    }

    // write O = acc / l
    #pragma unroll
    for (int i = 0; i < 4; i++) {
        float inv = 1.f / l_i[i];
        float4 o = make_float4(accv[i][0] * inv, accv[i][1] * inv,
                               accv[i][2] * inv, accv[i][3] * inv);
        *(float4*)&z[(rowbase + q0 + tq * 4 + i) * D_MODEL + colbase + tk * 4] = o;
    }
}

// ------------------------------------------------------------------
// LayerNorm + residual. mode 0: out = LN(a)*g+be + r ; mode 1: out = LN(a+r)*g+be
// grid = num_rows, block = 256, D_MODEL = 1024 (4 elems/thread)
// ------------------------------------------------------------------
__global__ __launch_bounds__(256) void ln_res(
    const float* __restrict__ a, const float* __restrict__ r,
    const float* __restrict__ g, const float* __restrict__ be,
    float* __restrict__ out, int mode)
{
    __shared__ float redls[8];
    const int row = blockIdx.x;
    const int t   = threadIdx.x;
    const float* pa = a + (size_t)row * D_MODEL;
    const float* pr = r + (size_t)row * D_MODEL;

    float vals[4];
    float s = 0.f, sq = 0.f;
    #pragma unroll
    for (int i = 0; i < 4; i++) {
        int c = t + 256 * i;
        float x = pa[c];
        if (mode == 1) x += pr[c];
        vals[i] = x; s += x; sq += x * x;
    }
    #pragma unroll
    for (int off = 32; off > 0; off >>= 1) {
        s  += __shfl_down(s, off);
        sq += __shfl_down(sq, off);
    }
    if ((t & 63) == 0) { redls[t >> 6] = s; redls[4 + (t >> 6)] = sq; }
    __syncthreads();
    s  = redls[0] + redls[1] + redls[2] + redls[3];
    sq = redls[4] + redls[5] + redls[6] + redls[7];

    const float mu  = s * (1.f / 1024.f);
    const float var = sq * (1.f / 1024.f) - mu * mu;
    const float rs  = rsqrtf(var + LNEPS);
    #pragma unroll
    for (int i = 0; i < 4; i++) {
        int c = t + 256 * i;
        float y = (vals[i] - mu) * rs * g[c] + be[c];
        if (mode == 0) y += pr[c];
        out[(size_t)row * D_MODEL + c] = y;
    }
}

// ------------------------------------------------------------------
extern "C" void kernel_launch(void* const* d_in, const int* in_sizes, int n_in,
                              void* d_out, int out_size, void* d_ws, size_t ws_size,
                              hipStream_t stream)
{
    const float* q    = (const float*)d_in[0];
    const float* k    = (const float*)d_in[1];
    const float* v    = (const float*)d_in[2];
    // d_in[3] = time_lengths (unused by reference)
    const float* mask = (const float*)d_in[4];
    const float* Wq   = (const float*)d_in[5];
    const float* Wk   = (const float*)d_in[6];
    const float* Wv   = (const float*)d_in[7];
    const float* Wd   = (const float*)d_in[8];
    const float* W1   = (const float*)d_in[9];
    const float* b1   = (const float*)d_in[10];
    const float* W2   = (const float*)d_in[11];
    const float* b2   = (const float*)d_in[12];
    const float* g1   = (const float*)d_in[13];
    const float* be1  = (const float*)d_in[14];
    const float* g2   = (const float*)d_in[15];
    const float* be2  = (const float*)d_in[16];
    float* out = (float*)d_out;

    float* wsf = (float*)d_ws;
    const size_t ND = (size_t)4096 * 1024;
    float* qh = wsf;            // 16 MiB
    float* kh = wsf + ND;       // 16 MiB
    float* vh = wsf + 2 * ND;   // 16 MiB
    float* z  = wsf + 3 * ND;   // 16 MiB
    float* h1 = wsf + 4 * ND;   // 64 MiB (4096 x 4096)
    float* zd = qh;             // reuse (qh dead after attention)
    float* x  = kh;             // reuse (kh dead after attention)
    float* y  = vh;             // reuse (vh dead after FF1)

    const dim3 blk(256);
    const dim3 gProj(1024 / 64, 4096 / 64);   // N=1024 GEMMs
    const dim3 gFF1(4096 / 64, 4096 / 64);    // N=4096

    gemm_f32<<<gProj, blk, 0, stream>>>(q, Wq, qh, 4096, 1024, 1024, nullptr, 0);
    gemm_f32<<<gProj, blk, 0, stream>>>(k, Wk, kh, 4096, 1024, 1024, nullptr, 0);
    gemm_f32<<<gProj, blk, 0, stream>>>(v, Wv, vh, 4096, 1024, 1024, nullptr, 0);

    attn_f32<<<dim3(2 * 16 * 32), blk, 0, stream>>>(qh, kh, vh, mask, z);

    gemm_f32<<<gProj, blk, 0, stream>>>(z, Wd, zd, 4096, 1024, 1024, nullptr, 0);
    ln_res<<<dim3(4096), blk, 0, stream>>>(zd, q, g1, be1, x, 0);

    gemm_f32<<<gFF1, blk, 0, stream>>>(x, W1, h1, 4096, 4096, 1024, b1, 2);
    gemm_f32<<<gProj, blk, 0, stream>>>(h1, W2, y, 4096, 1024, 4096, b2, 1);

    ln_res<<<dim3(4096), blk, 0, stream>>>(y, x, g2, be2, out, 1);
}

// Round 2
// 571.126 us; speedup vs baseline: 3.7067x; 3.7067x over previous
//
#include <hip/hip_runtime.h>
#include <hip/hip_bf16.h>

// EncoderCell, bf16-MFMA version.
//   gemm_bf16: 128x128 tile, 4 waves (2x2 of 64x64), BK=32, global_load_lds(16B)
//              staging (m97 structure), A[M,K] bf16 x Bt[N,K] bf16 -> C fp32/bf16,
//              epilogue: none / +bias / +bias+relu, batched via blockIdx.z strides.
//   attn_mfma: flash attention, block=(b,h,64 q-rows), 64-key tiles, QK^T and PV on
//              MFMA; P goes C-layout -> LDS(stride 72, 2-way-alias-free) -> A-layout.
//   ln_res:    mode 0: out=LN(a)+r (fp32 + optional bf16 copy); mode 1: out=LN(a+r).
// ws layout (MiB): [0,24) qb|kb|vb -> reused as vhT|zb|xb ; [24,30) Wq/k/vT ;
//   [30,32) WdT ; [32,40) W1T ; [40,48) W2T ; [48,72) qh|kh|vh -> zd reuses [48,64) ;
//   [64,80) y ; [80,96) x ; [96,128) h1.  Total = 128 MiB.

#define SEQ 2048
#define DM  1024
#define LNEPS 1e-5f

typedef __attribute__((ext_vector_type(8))) short bf16x8;
typedef __attribute__((ext_vector_type(4))) float f32x4;
typedef __attribute__((ext_vector_type(8))) unsigned short u16x8;

#define GAS __attribute__((address_space(1)))
#define LAS __attribute__((address_space(3)))

static __device__ __forceinline__ void gl_lds16(const unsigned short* g, unsigned short* l) {
    // lds dest is wave-uniform base; HW writes lane i at base + i*16B
    __builtin_amdgcn_global_load_lds((const GAS void*)g, (LAS void*)l, 16, 0, 0);
}

static __device__ __forceinline__ unsigned short f2bf(float f) {
    unsigned u = __builtin_bit_cast(unsigned, f);
    u += 0x7fffu + ((u >> 16) & 1u);   // RNE
    return (unsigned short)(u >> 16);
}

// ------------------------------------------------------------------
// C[M,N] = A[M,K] @ Bt[N,K]^T ; out fp32 (Cf) or bf16 (Cb); ep: 0 none, 1 +bias, 2 +bias,relu
// ------------------------------------------------------------------
__global__ __launch_bounds__(256) void gemm_bf16(
    const unsigned short* __restrict__ A, const unsigned short* __restrict__ Bt,
    float* __restrict__ Cf, unsigned short* __restrict__ Cb,
    int M, int N, int K, size_t sA, size_t sB, size_t sC,
    const float* __restrict__ bias, int ep)
{
    __shared__ unsigned short As[128 * 32];
    __shared__ unsigned short Bs[128 * 32];

    const int t = threadIdx.x, lane = t & 63, w = t >> 6;
    const int wm = w >> 1, wn = w & 1;
    const int m0 = blockIdx.y * 128, n0 = blockIdx.x * 128;
    A  += (size_t)blockIdx.z * sA;
    Bt += (size_t)blockIdx.z * sB;
    const size_t cbase = (size_t)blockIdx.z * sC;
    const int l15 = lane & 15, l16 = lane >> 4;
    const int ar = lane >> 2, ac = (lane & 3) * 8;   // staging: 16 rows x 4 chunks / wave-instr

    f32x4 acc[4][4];
    #pragma unroll
    for (int i = 0; i < 4; i++)
        #pragma unroll
        for (int j = 0; j < 4; j++)
            acc[i][j] = (f32x4){0.f, 0.f, 0.f, 0.f};

    for (int k0 = 0; k0 < K; k0 += 32) {
        __syncthreads();
        #pragma unroll
        for (int i = 0; i < 2; i++) {
            const int rg = w * 2 + i;   // 16-row group
            gl_lds16(&A [(size_t)(m0 + rg * 16 + ar) * K + k0 + ac], &As[rg * 512]);
            gl_lds16(&Bt[(size_t)(n0 + rg * 16 + ar) * K + k0 + ac], &Bs[rg * 512]);
        }
        __syncthreads();   // drains vmcnt before barrier -> staged data visible

        bf16x8 af[4], bfr[4];
        #pragma unroll
        for (int i = 0; i < 4; i++) {
            af[i]  = *(const bf16x8*)&As[(wm * 64 + i * 16 + l15) * 32 + l16 * 8];
            bfr[i] = *(const bf16x8*)&Bs[(wn * 64 + i * 16 + l15) * 32 + l16 * 8];
        }
        #pragma unroll
        for (int mi = 0; mi < 4; mi++)
            #pragma unroll
            for (int ni = 0; ni < 4; ni++)
                acc[mi][ni] = __builtin_amdgcn_mfma_f32_16x16x32_bf16(
                    af[mi], bfr[ni], acc[mi][ni], 0, 0, 0);
    }

    // epilogue: C/D layout row=(lane>>4)*4+r, col=lane&15
    #pragma unroll
    for (int ni = 0; ni < 4; ni++) {
        const int col = n0 + wn * 64 + ni * 16 + l15;
        const float bv = ep ? bias[col] : 0.f;
        #pragma unroll
        for (int mi = 0; mi < 4; mi++) {
            #pragma unroll
            for (int r = 0; r < 4; r++) {
                const int row = m0 + wm * 64 + mi * 16 + l16 * 4 + r;
                float vv = acc[mi][ni][r] + bv;
                if (ep == 2) vv = fmaxf(vv, 0.f);
                if (Cf) Cf[cbase + (size_t)row * N + col] = vv;
                else    Cb[cbase + (size_t)row * N + col] = f2bf(vv);
            }
        }
    }
}

// ------------------------------------------------------------------
// Flash attention. grid = B*H*(SEQ/64) 1D. block 256 = 4 waves, wave w owns q rows [w*16,w*16+16).
// qh,kh bf16 [B*S][DM]; vhT bf16 [(b*16+h)*64 + d][SEQ]; z bf16 [B*S][DM].
// ------------------------------------------------------------------
__global__ __launch_bounds__(256) void attn_mfma(
    const unsigned short* __restrict__ qh, const unsigned short* __restrict__ kh,
    const unsigned short* __restrict__ vhT, const float* __restrict__ mask,
    unsigned short* __restrict__ z)
{
    __shared__ unsigned short Qs[64 * 64];
    __shared__ unsigned short Ks[64 * 64];
    __shared__ unsigned short Vst[64 * 64];   // V^T tile: [d][key]
    __shared__ unsigned short Ps[64 * 72];    // stride 72 (144B, 16B-aligned, 2-way alias only)

    const int t = threadIdx.x, lane = t & 63, w = t >> 6;
    const int bid = blockIdx.x;
    const int qt = bid & 31, h = (bid >> 5) & 15, b = bid >> 9;
    const int q0 = qt * 64, qr = w * 16;
    const int l15 = lane & 15, l16 = lane >> 4;
    const int rr = lane >> 3, cchunk = (lane & 7) * 8;  // staging: 8 rows x 8 chunks / wave-instr

    // stage Q tile (64 rows x 64 d)
    #pragma unroll
    for (int i = 0; i < 2; i++) {
        const int rg = w * 2 + i;
        gl_lds16(&qh[(size_t)(b * SEQ + q0 + rg * 8 + rr) * DM + h * 64 + cchunk], &Qs[rg * 512]);
    }
    __syncthreads();
    const bf16x8 aQ0 = *(const bf16x8*)&Qs[(qr + l15) * 64 + l16 * 8];
    const bf16x8 aQ1 = *(const bf16x8*)&Qs[(qr + l15) * 64 + l16 * 8 + 32];

    float m_i[4], l_i[4];
    f32x4 o4[4];
    #pragma unroll
    for (int r = 0; r < 4; r++) { m_i[r] = -1e30f; l_i[r] = 0.f; }
    #pragma unroll
    for (int ni = 0; ni < 4; ni++) o4[ni] = (f32x4){0.f, 0.f, 0.f, 0.f};

    for (int kt = 0; kt < SEQ / 64; kt++) {
        const int k0 = kt * 64;
        __syncthreads();   // all waves done reading Ks/Vst of prev iter
        #pragma unroll
        for (int i = 0; i < 2; i++) {
            const int rg = w * 2 + i;
            gl_lds16(&kh[(size_t)(b * SEQ + k0 + rg * 8 + rr) * DM + h * 64 + cchunk], &Ks[rg * 512]);
            gl_lds16(&vhT[(size_t)((b * 16 + h) * 64 + rg * 8 + rr) * SEQ + k0 + cchunk], &Vst[rg * 512]);
        }
        __syncthreads();

        // S = Q K^T : 4 key-tiles of 16
        f32x4 s4[4];
        #pragma unroll
        for (int ni = 0; ni < 4; ni++) {
            const bf16x8 bK0 = *(const bf16x8*)&Ks[(ni * 16 + l15) * 64 + l16 * 8];
            const bf16x8 bK1 = *(const bf16x8*)&Ks[(ni * 16 + l15) * 64 + l16 * 8 + 32];
            f32x4 a0 = (f32x4){0.f, 0.f, 0.f, 0.f};
            a0 = __builtin_amdgcn_mfma_f32_16x16x32_bf16(aQ0, bK0, a0, 0, 0, 0);
            s4[ni] = __builtin_amdgcn_mfma_f32_16x16x32_bf16(aQ1, bK1, a0, 0, 0, 0);
        }

        // scale + mask (C layout: row=l16*4+r, col=ni*16+l15)
        float sv[4][4];
        #pragma unroll
        for (int ni = 0; ni < 4; ni++)
            #pragma unroll
            for (int r = 0; r < 4; r++)
                sv[ni][r] = s4[ni][r] * 0.125f +
                    mask[(size_t)(q0 + qr + l16 * 4 + r) * SEQ + k0 + ni * 16 + l15];

        // online softmax per owned row r; 16-lane butterfly within col group
        #pragma unroll
        for (int r = 0; r < 4; r++) {
            float rm = fmaxf(fmaxf(sv[0][r], sv[1][r]), fmaxf(sv[2][r], sv[3][r]));
            #pragma unroll
            for (int off = 1; off < 16; off <<= 1) rm = fmaxf(rm, __shfl_xor(rm, off));
            const float mnew  = fmaxf(m_i[r], rm);
            const float alpha = __expf(m_i[r] - mnew);
            m_i[r] = mnew;
            float ps = 0.f;
            #pragma unroll
            for (int ni = 0; ni < 4; ni++) {
                const float p = __expf(sv[ni][r] - mnew);
                Ps[(qr + l16 * 4 + r) * 72 + ni * 16 + l15] = f2bf(p);
                ps += p;
            }
            #pragma unroll
            for (int off = 1; off < 16; off <<= 1) ps += __shfl_xor(ps, off);
            l_i[r] = l_i[r] * alpha + ps;
            #pragma unroll
            for (int ni = 0; ni < 4; ni++) o4[ni][r] *= alpha;
        }

        // PV: Ps rows are wave-private; compiler orders LDS ops within the wave
        const bf16x8 aP0 = *(const bf16x8*)&Ps[(qr + l15) * 72 + l16 * 8];
        const bf16x8 aP1 = *(const bf16x8*)&Ps[(qr + l15) * 72 + l16 * 8 + 32];
        #pragma unroll
        for (int ni = 0; ni < 4; ni++) {
            const bf16x8 bV0 = *(const bf16x8*)&Vst[(ni * 16 + l15) * 64 + l16 * 8];
            const bf16x8 bV1 = *(const bf16x8*)&Vst[(ni * 16 + l15) * 64 + l16 * 8 + 32];
            o4[ni] = __builtin_amdgcn_mfma_f32_16x16x32_bf16(aP0, bV0, o4[ni], 0, 0, 0);
            o4[ni] = __builtin_amdgcn_mfma_f32_16x16x32_bf16(aP1, bV1, o4[ni], 0, 0, 0);
        }
    }

    #pragma unroll
    for (int r = 0; r < 4; r++) {
        const float inv = 1.f / l_i[r];
        #pragma unroll
        for (int ni = 0; ni < 4; ni++)
            z[(size_t)(b * SEQ + q0 + qr + l16 * 4 + r) * DM + h * 64 + ni * 16 + l15] =
                f2bf(o4[ni][r] * inv);
    }
}

// ------------------------------------------------------------------
// casts / transposes
// ------------------------------------------------------------------
__global__ __launch_bounds__(256) void cast3_bf16(
    const float* __restrict__ a0, const float* __restrict__ a1, const float* __restrict__ a2,
    unsigned short* __restrict__ out)
{
    const float* src = blockIdx.z == 0 ? a0 : (blockIdx.z == 1 ? a1 : a2);
    const size_t i = ((size_t)blockIdx.x * 256 + threadIdx.x) * 4;
    const float4 v = *(const float4*)&src[i];
    ushort4 o; o.x = f2bf(v.x); o.y = f2bf(v.y); o.z = f2bf(v.z); o.w = f2bf(v.w);
    *(ushort4*)&out[(size_t)blockIdx.z * ((size_t)SEQ * 2 * DM) + i] = o;
}

// W[K][N] fp32 -> Wt[N][K] bf16 ; grid (N/64, K/64)
__global__ __launch_bounds__(256) void transpose_cast(
    const float* __restrict__ W, unsigned short* __restrict__ Wt, int K, int N)
{
    __shared__ float ts[64][65];
    const int n0 = blockIdx.x * 64, k0 = blockIdx.y * 64;
    const int t = threadIdx.x, r = t >> 4, c4 = (t & 15) * 4;
    #pragma unroll
    for (int i = 0; i < 4; i++) {
        const float4 v = *(const float4*)&W[(size_t)(k0 + r + i * 16) * N + n0 + c4];
        ts[r + i * 16][c4 + 0] = v.x; ts[r + i * 16][c4 + 1] = v.y;
        ts[r + i * 16][c4 + 2] = v.z; ts[r + i * 16][c4 + 3] = v.w;
    }
    __syncthreads();
    #pragma unroll
    for (int i = 0; i < 4; i++) {
        const int n = r + i * 16;
        ushort4 o;
        o.x = f2bf(ts[c4 + 0][n]); o.y = f2bf(ts[c4 + 1][n]);
        o.z = f2bf(ts[c4 + 2][n]); o.w = f2bf(ts[c4 + 3][n]);
        *(ushort4*)&Wt[(size_t)(n0 + n) * K + k0 + c4] = o;
    }
}

// vh bf16 [B*S][DM] -> vhT bf16 [(b*16+h)*64 + d][SEQ] ; grid (S/64, H, B)
__global__ __launch_bounds__(256) void transpose_v(
    const unsigned short* __restrict__ vh, unsigned short* __restrict__ vhT)
{
    __shared__ unsigned short ts[64][80];
    const int s0 = blockIdx.x * 64, h = blockIdx.y, b = blockIdx.z;
    const int t = threadIdx.x, rr = t >> 3, c8 = (t & 7) * 8;
    #pragma unroll
    for (int i = 0; i < 2; i++) {
        const int sr = rr + i * 32;
        *(uint4*)&ts[sr][c8] = *(const uint4*)&vh[(size_t)(b * SEQ + s0 + sr) * DM + h * 64 + c8];
    }
    __syncthreads();
    #pragma unroll
    for (int i = 0; i < 2; i++) {
        const int dr = rr + i * 32;
        u16x8 ov;
        #pragma unroll
        for (int j = 0; j < 8; j++) ov[j] = ts[c8 + j][dr];
        *(u16x8*)&vhT[(size_t)((b * 16 + h) * 64 + dr) * SEQ + s0 + c8] = ov;
    }
}

// ------------------------------------------------------------------
// LayerNorm + residual. mode 0: out=LN(a)*g+be + r (+bf16 copy outb); mode 1: out=LN(a+r)*g+be
// ------------------------------------------------------------------
__global__ __launch_bounds__(256) void ln_res(
    const float* __restrict__ a, const float* __restrict__ r,
    const float* __restrict__ g, const float* __restrict__ be,
    float* __restrict__ out, unsigned short* __restrict__ outb, int mode)
{
    __shared__ float redls[8];
    const int row = blockIdx.x, t = threadIdx.x;
    const float* pa = a + (size_t)row * DM;
    const float* pr = r + (size_t)row * DM;

    float vals[4], s = 0.f, sq = 0.f;
    #pragma unroll
    for (int i = 0; i < 4; i++) {
        const int c = t + 256 * i;
        float x = pa[c];
        if (mode == 1) x += pr[c];
        vals[i] = x; s += x; sq += x * x;
    }
    #pragma unroll
    for (int off = 32; off > 0; off >>= 1) { s += __shfl_down(s, off); sq += __shfl_down(sq, off); }
    if ((t & 63) == 0) { redls[t >> 6] = s; redls[4 + (t >> 6)] = sq; }
    __syncthreads();
    s  = redls[0] + redls[1] + redls[2] + redls[3];
    sq = redls[4] + redls[5] + redls[6] + redls[7];

    const float mu  = s * (1.f / 1024.f);
    const float var = sq * (1.f / 1024.f) - mu * mu;
    const float rs  = rsqrtf(var + LNEPS);
    #pragma unroll
    for (int i = 0; i < 4; i++) {
        const int c = t + 256 * i;
        float y = (vals[i] - mu) * rs * g[c] + be[c];
        if (mode == 0) y += pr[c];
        out[(size_t)row * DM + c] = y;
        if (outb) outb[(size_t)row * DM + c] = f2bf(y);
    }
}

// ------------------------------------------------------------------
extern "C" void kernel_launch(void* const* d_in, const int* in_sizes, int n_in,
                              void* d_out, int out_size, void* d_ws, size_t ws_size,
                              hipStream_t stream)
{
    const float* q    = (const float*)d_in[0];
    const float* k    = (const float*)d_in[1];
    const float* v    = (const float*)d_in[2];
    const float* mask = (const float*)d_in[4];
    const float* Wq   = (const float*)d_in[5];
    const float* Wk   = (const float*)d_in[6];
    const float* Wv   = (const float*)d_in[7];
    const float* Wd   = (const float*)d_in[8];
    const float* W1   = (const float*)d_in[9];
    const float* b1   = (const float*)d_in[10];
    const float* W2   = (const float*)d_in[11];
    const float* b2   = (const float*)d_in[12];
    const float* g1   = (const float*)d_in[13];
    const float* be1  = (const float*)d_in[14];
    const float* g2   = (const float*)d_in[15];
    const float* be2  = (const float*)d_in[16];
    float* out = (float*)d_out;

    char* WS = (char*)d_ws;
    const size_t MiB = 1u << 20;
    const size_t ND  = (size_t)4096 * 1024;       // rows x DM

    unsigned short* qb  = (unsigned short*)(WS + 0);          // 24 MiB: qb|kb|vb
    unsigned short* vhT = (unsigned short*)(WS + 0);          //  8 MiB (reuse qb)
    unsigned short* zb  = (unsigned short*)(WS + 8 * MiB);    //  8 MiB (reuse kb)
    unsigned short* xb  = (unsigned short*)(WS + 16 * MiB);   //  8 MiB (reuse vb)
    unsigned short* Wqt = (unsigned short*)(WS + 24 * MiB);   //  6 MiB: WqT|WkT|WvT
    unsigned short* Wdt = (unsigned short*)(WS + 30 * MiB);   //  2 MiB
    unsigned short* W1t = (unsigned short*)(WS + 32 * MiB);   //  8 MiB
    unsigned short* W2t = (unsigned short*)(WS + 40 * MiB);   //  8 MiB
    unsigned short* qh  = (unsigned short*)(WS + 48 * MiB);   // 24 MiB: qh|kh|vh
    float*          zd  = (float*)(WS + 48 * MiB);            // 16 MiB (reuse qh|kh)
    float*          y   = (float*)(WS + 64 * MiB);            // 16 MiB (reuse vh+)
    float*          x   = (float*)(WS + 80 * MiB);            // 16 MiB
    unsigned short* h1  = (unsigned short*)(WS + 96 * MiB);   // 32 MiB

    unsigned short* kh = qh + ND;
    unsigned short* vh = qh + 2 * ND;

    const dim3 blk(256);

    // bf16 casts + weight transposes
    cast3_bf16<<<dim3(4096, 1, 3), blk, 0, stream>>>(q, k, v, qb);
    transpose_cast<<<dim3(16, 16), blk, 0, stream>>>(Wq, Wqt,                1024, 1024);
    transpose_cast<<<dim3(16, 16), blk, 0, stream>>>(Wk, Wqt + 1024 * 1024,  1024, 1024);
    transpose_cast<<<dim3(16, 16), blk, 0, stream>>>(Wv, Wqt + 2 * 1024 * 1024, 1024, 1024);
    transpose_cast<<<dim3(16, 16), blk, 0, stream>>>(Wd, Wdt, 1024, 1024);
    transpose_cast<<<dim3(64, 16), blk, 0, stream>>>(W1, W1t, 1024, 4096);
    transpose_cast<<<dim3(16, 64), blk, 0, stream>>>(W2, W2t, 4096, 1024);

    // QKV projections (batched z=3), bf16 out
    gemm_bf16<<<dim3(8, 32, 3), blk, 0, stream>>>(qb, Wqt, nullptr, qh,
        4096, 1024, 1024, ND, (size_t)1024 * 1024, ND, nullptr, 0);

    // V^T for PV B-operand
    transpose_v<<<dim3(32, 16, 2), blk, 0, stream>>>(vh, vhT);

    // attention -> zb bf16
    attn_mfma<<<dim3(1024), blk, 0, stream>>>(qh, kh, vhT, mask, zb);

    // out-proj -> zd fp32
    gemm_bf16<<<dim3(8, 32, 1), blk, 0, stream>>>(zb, Wdt, zd, nullptr,
        4096, 1024, 1024, 0, 0, 0, nullptr, 0);

    // LN1: x = LN(zd)+q (fp32 + bf16 copy)
    ln_res<<<dim3(4096), blk, 0, stream>>>(zd, q, g1, be1, x, xb, 0);

    // FFN
    gemm_bf16<<<dim3(32, 32, 1), blk, 0, stream>>>(xb, W1t, nullptr, h1,
        4096, 4096, 1024, 0, 0, 0, b1, 2);
    gemm_bf16<<<dim3(8, 32, 1), blk, 0, stream>>>(h1, W2t, y, nullptr,
        4096, 1024, 4096, 0, 0, 0, b2, 1);

    // LN2
    ln_res<<<dim3(4096), blk, 0, stream>>>(y, x, g2, be2, out, nullptr, 1);
}